// Round 3
// baseline (423.821 us; speedup 1.0000x reference)
//
#include <hip/hip_runtime.h>
#include <hip/hip_bf16.h>

#define DM 2048
#define NH 4
#define DI 64
#define TQS 4096
#define TKS 4096
#define BB 2
#define MROWS 8192  // B*T

typedef __attribute__((ext_vector_type(4))) float f32x4;
typedef __attribute__((ext_vector_type(8))) short bf16x8;

__device__ __forceinline__ short f2bf(float f) {
  __hip_bfloat16 h = __float2bfloat16(f);
  return __builtin_bit_cast(short, h);
}

__device__ __forceinline__ bf16x8 cvt8(f32x4 a, f32x4 b) {
  bf16x8 r;
  r[0] = f2bf(a[0]); r[1] = f2bf(a[1]); r[2] = f2bf(a[2]); r[3] = f2bf(a[3]);
  r[4] = f2bf(b[0]); r[5] = f2bf(b[1]); r[6] = f2bf(b[2]); r[7] = f2bf(b[3]);
  return r;
}

// WqwT[320][2048]: rows 0-255 = Wq cols, 256-259 = Ww cols, 260-319 = 0.
__global__ __launch_bounds__(256) void transpose_qw(const float* __restrict__ Wq,
                                                    const float* __restrict__ Ww,
                                                    short* __restrict__ WT) {
  int idx = blockIdx.x * 256 + threadIdx.x;  // n*2048 + k
  int n = idx >> 11, k = idx & 2047;
  float v = 0.f;
  if (n < 256) v = Wq[(size_t)k * 256 + n];
  else if (n < 260) v = Ww[(size_t)k * 4 + (n - 256)];
  WT[idx] = f2bf(v);
}

// WkT[64][2048]
__global__ __launch_bounds__(256) void transpose_k(const float* __restrict__ Wk,
                                                   short* __restrict__ WT) {
  int idx = blockIdx.x * 256 + threadIdx.x;
  int n = idx >> 11, k = idx & 2047;
  WT[idx] = f2bf(Wk[(size_t)k * 64 + n]);
}

// One wave: 16 rows x 64 cols, K=2048. Small register footprint (~100 VGPR)
// so 4+ waves/SIMD stay resident — TLP hides L2/L3 latency, not ILP.
__device__ __forceinline__ void proj16(const float* __restrict__ X,
                                       const short* __restrict__ WT,
                                       short* __restrict__ O,
                                       float* __restrict__ wI,
                                       int m0, int nt, int ldo, bool wtile) {
  const int lane = threadIdx.x & 63;
  const int l15 = lane & 15, quad = lane >> 4;

  const float* xrow = X + (size_t)(m0 + l15) * DM + quad * 8;
  const short* wrow = WT + (size_t)(nt * 64 + l15) * DM + quad * 8;

  const f32x4 z = {0.f, 0.f, 0.f, 0.f};
  f32x4 acc[4];
#pragma unroll
  for (int j = 0; j < 4; ++j) acc[j] = z;

  f32x4 a0 = *(const f32x4*)xrow;
  f32x4 a1 = *(const f32x4*)(xrow + 4);
  bf16x8 bcur[4];
#pragma unroll
  for (int j = 0; j < 4; ++j) bcur[j] = *(const bf16x8*)(wrow + (size_t)j * 16 * DM);

#pragma unroll 2
  for (int ks = 0; ks < DM / 32; ++ks) {
    f32x4 an0 = a0, an1 = a1;
    bf16x8 bnxt[4];
    if (ks < DM / 32 - 1) {
      const float* xp = xrow + (ks + 1) * 32;
      an0 = *(const f32x4*)xp;
      an1 = *(const f32x4*)(xp + 4);
#pragma unroll
      for (int j = 0; j < 4; ++j)
        bnxt[j] = *(const bf16x8*)(wrow + (size_t)j * 16 * DM + (ks + 1) * 32);
    } else {
#pragma unroll
      for (int j = 0; j < 4; ++j) bnxt[j] = bcur[j];
    }
    bf16x8 abf = cvt8(a0, a1);
#pragma unroll
    for (int j = 0; j < 4; ++j)
      acc[j] = __builtin_amdgcn_mfma_f32_16x16x32_bf16(abf, bcur[j], acc[j], 0, 0, 0);
    a0 = an0; a1 = an1;
#pragma unroll
    for (int j = 0; j < 4; ++j) bcur[j] = bnxt[j];
  }

  // C/D: row = quad*4 + r, col = l15
  if (wtile) {
    if (l15 < 4) {
#pragma unroll
      for (int r = 0; r < 4; ++r)
        wI[(size_t)(m0 + quad * 4 + r) * NH + l15] = acc[0][r];
    }
  } else {
#pragma unroll
    for (int j = 0; j < 4; ++j)
#pragma unroll
      for (int r = 0; r < 4; ++r)
        O[(size_t)(m0 + quad * 4 + r) * ldo + nt * 64 + j * 16 + l15] =
            f2bf(acc[j][r]);
  }
}

// Blocks 0..511: q-path, 16 rows/block, 5 waves = 5 column tiles (A shared in L1).
// Blocks 512..614: k-path, 80 rows/block (wave w -> rows +w*16), 1 column tile.
__global__ __launch_bounds__(320, 4) void proj_fused(const float* __restrict__ xq,
                                                     const float* __restrict__ xk,
                                                     const short* __restrict__ WqwT,
                                                     const short* __restrict__ WkT,
                                                     short* __restrict__ qb,
                                                     short* __restrict__ kb,
                                                     float* __restrict__ wIb) {
  const int wave = threadIdx.x >> 6;
  if (blockIdx.x < 512) {
    const int m0 = blockIdx.x * 16;
    proj16(xq, WqwT, qb, wIb, m0, wave, 256, wave == 4);
  } else {
    const int m0 = (blockIdx.x - 512) * 80 + wave * 16;
    if (m0 >= MROWS) return;
    proj16(xk, WkT, kb, nullptr, m0, 0, 64, false);
  }
}

// out[b][q][k] = sum_h wI[b,q,h] * relu(qb[b,q,h,:] . kb[b,k,:])
// 128x128 tile/block, 4 waves of 64x64. No LDS/barriers; af double-buffered over heads.
__global__ __launch_bounds__(256, 2) void score_kernel(const short* __restrict__ qb,
                                                       const short* __restrict__ kb,
                                                       const float* __restrict__ wI,
                                                       float* __restrict__ out) {
  const int b = blockIdx.z;
  const int qt = blockIdx.y;
  const int kt = blockIdx.x;
  const int tid = threadIdx.x;
  const int wave = tid >> 6, lane = tid & 63;
  const int wm = wave >> 1, wn = wave & 1;
  const int l15 = lane & 15, quad = lane >> 4;

  bf16x8 bf[4][2];
  {
    const short* kbase =
        kb + (size_t)(b * TKS + kt * 128 + wn * 64 + l15) * DI + quad * 8;
#pragma unroll
    for (int j = 0; j < 4; ++j)
#pragma unroll
      for (int ks = 0; ks < 2; ++ks)
        bf[j][ks] = *(const bf16x8*)(kbase + j * 16 * DI + ks * 32);
  }

  const f32x4 z = {0.f, 0.f, 0.f, 0.f};
  f32x4 facc[4][4];
#pragma unroll
  for (int i = 0; i < 4; ++i)
#pragma unroll
    for (int j = 0; j < 4; ++j) facc[i][j] = z;

  const short* qbase =
      qb + (size_t)(b * TQS + qt * 128 + wm * 64 + l15) * (NH * DI) + quad * 8;
  const float* wbase = wI + (size_t)(b * TQS + qt * 128 + wm * 64 + quad * 4) * NH;

  bf16x8 af[2][4][2];
#pragma unroll
  for (int i = 0; i < 4; ++i)
#pragma unroll
    for (int ks = 0; ks < 2; ++ks)
      af[0][i][ks] = *(const bf16x8*)(qbase + i * 16 * (NH * DI) + ks * 32);

#pragma unroll
  for (int h = 0; h < NH; ++h) {
    if (h < NH - 1) {
#pragma unroll
      for (int i = 0; i < 4; ++i)
#pragma unroll
        for (int ks = 0; ks < 2; ++ks)
          af[(h + 1) & 1][i][ks] =
              *(const bf16x8*)(qbase + (h + 1) * DI + i * 16 * (NH * DI) + ks * 32);
    }

    f32x4 acc[4][4];
#pragma unroll
    for (int i = 0; i < 4; ++i)
#pragma unroll
      for (int j = 0; j < 4; ++j) acc[i][j] = z;

#pragma unroll
    for (int ks = 0; ks < 2; ++ks)
#pragma unroll
      for (int i = 0; i < 4; ++i)
#pragma unroll
        for (int j = 0; j < 4; ++j)
          acc[i][j] = __builtin_amdgcn_mfma_f32_16x16x32_bf16(
              af[h & 1][i][ks], bf[j][ks], acc[i][j], 0, 0, 0);

#pragma unroll
    for (int i = 0; i < 4; ++i) {
      float wv[4];
#pragma unroll
      for (int r = 0; r < 4; ++r) wv[r] = wbase[(i * 16 + r) * NH + h];
#pragma unroll
      for (int j = 0; j < 4; ++j)
#pragma unroll
        for (int r = 0; r < 4; ++r)
          facc[i][j][r] += wv[r] * fmaxf(acc[i][j][r], 0.f);
    }
  }

  float* obase = out + (size_t)b * TQS * TKS +
                 (size_t)(qt * 128 + wm * 64 + quad * 4) * TKS + kt * 128 + wn * 64 + l15;
#pragma unroll
  for (int i = 0; i < 4; ++i)
#pragma unroll
    for (int r = 0; r < 4; ++r)
#pragma unroll
      for (int j = 0; j < 4; ++j)
        __builtin_nontemporal_store(facc[i][j][r],
                                    &obase[(size_t)(i * 16 + r) * TKS + j * 16]);
}

extern "C" void kernel_launch(void* const* d_in, const int* in_sizes, int n_in,
                              void* d_out, int out_size, void* d_ws, size_t ws_size,
                              hipStream_t stream) {
  const float* x_q = (const float*)d_in[0];  // [2,4096,2048]
  const float* x_k = (const float*)d_in[1];  // [2,4096,2048]
  const float* Wq  = (const float*)d_in[2];  // [2048,256]
  const float* Ww  = (const float*)d_in[3];  // [2048,4]
  const float* Wk  = (const float*)d_in[4];  // [2048,64]
  float* out = (float*)d_out;                // [2,4096,4096]

  char* ws = (char*)d_ws;
  short* qbuf = (short*)(ws);                              // 8192*256 bf16 = 4 MB
  short* kbuf = (short*)(ws + (4u << 20));                 // 8192*64  bf16 = 1 MB
  float* wIb  = (float*)(ws + (5u << 20));                 // 8192*4 f32 = 128 KB
  short* WqwT = (short*)(ws + (5u << 20) + (128u << 10));  // 320*2048 bf16 = 1.25 MB
  short* WkT  = (short*)(ws + (7u << 20));                 // 64*2048 bf16 = 256 KB

  transpose_qw<<<(320 * 2048) / 256, 256, 0, stream>>>(Wq, Ww, WqwT);
  transpose_k<<<(64 * 2048) / 256, 256, 0, stream>>>(Wk, WkT);

  // q: 512 blocks (16 rows x 320 cols); k: 103 blocks (80 rows x 64 cols)
  proj_fused<<<512 + 103, 320, 0, stream>>>(x_q, x_k, WqwT, WkT, qbuf, kbuf, wIb);

  score_kernel<<<dim3(TKS / 128, TQS / 128, BB), 256, 0, stream>>>(qbuf, kbuf, wIb, out);
}